// Round 5
// baseline (116.215 us; speedup 1.0000x reference)
//
#include <hip/hip_runtime.h>
#include <stdint.h>
#include <stdio.h>
#include <stdlib.h>
#include <unistd.h>
#include <math.h>

// ============================================================================
// QonvLayer: out[b, c2, j, k, l] (4, 32, 32, 32, 32) fp32.
// Only j,k,l < 16 nonzero. c2<16 -> circuit(weights1) on patch offsets
// (0,0,0),(1,1,0),(0,1,1),(1,0,1); c2>=16 -> circuit(weights2) on offsets
// (1,1,1),(0,0,1),(1,0,0),(0,1,0). Input index = (2j+dj, 2k+dk, 2l+dl).
//
// value = <Z_0> = psi^T R psi (psi real, R = Re(U^dag Z0 U)) collapsed to an
// 81-coefficient double-angle form:
//   <Z_0> = sum_{e in {0,1,2}^4} G[e] * prod_t v_t[e_t],
//   v_t = (1, cos(pi*min(1,y_t)), sin(pi*min(1,y_t)))
// G built per weight set into a __device__ global (validated round 4).
//
// v5: 4 outputs/thread along l -> one float4 store; gather via 8 float4 loads
// (4 rows x 16 floats, even/odd elements split across the 4 outputs).
//
// Gate plan = _make_plan(1234) via the harness's own python (/proc/self/exe)
// + numpy (ground truth, validated round 3); C++ PCG64 replication fallback
// (known-suspect; +1000 sentinel on out[0] if python unavailable).
// ============================================================================

struct PlanArg {
    int n;
    // ops[i]: x = type (0=rot, 1=cnot)
    //         y = gate (0 RX,1 RY,2 RZ)   or ctrl wire
    //         z = wire                    or tgt wire
    //         w = weight flat index l*4+i or 0
    int4 ops[24];
};

__device__ float g_G[2][81];   // 81-coeff tensor per weight set

// ---------------------------------------------------------------------------
// Fallback: host-side replication of numpy default_rng(1234) (emergency only)
// ---------------------------------------------------------------------------
typedef unsigned __int128 u128_t;

namespace nprng {

struct Pcg64 {
    u128_t state, inc;
    bool has32; uint32_t buf32;

    void step() {
        const u128_t MULT =
            ((u128_t)0x2360ed051fc65da4ULL << 64) | (u128_t)0x4385df649fccf645ULL;
        state = state * MULT + inc;
    }
    uint64_t next64() {
        step();
        uint64_t hi = (uint64_t)(state >> 64), lo = (uint64_t)state;
        unsigned rot = (unsigned)(hi >> 58);
        uint64_t v = hi ^ lo;
        return (v >> rot) | (v << ((64u - rot) & 63u));
    }
    uint32_t next32() {
        if (has32) { has32 = false; return buf32; }
        uint64_t n = next64();
        has32 = true; buf32 = (uint32_t)(n >> 32);
        return (uint32_t)n;
    }
    double rnd() {
        return (double)(next64() >> 11) * (1.0 / 9007199254740992.0);
    }
    uint32_t lemire32(uint32_t rng) {
        uint32_t rng_excl = rng + 1u;
        uint64_t m = (uint64_t)next32() * (uint64_t)rng_excl;
        uint32_t leftover = (uint32_t)m;
        if (leftover < rng_excl) {
            uint32_t threshold = (uint32_t)((0xFFFFFFFFu - rng) % rng_excl);
            while (leftover < threshold) {
                m = (uint64_t)next32() * (uint64_t)rng_excl;
                leftover = (uint32_t)m;
            }
        }
        return (uint32_t)(m >> 32);
    }
    uint64_t bounded(uint64_t rng) {
        if (rng == 0) return 0;
        return (uint64_t)lemire32((uint32_t)rng);
    }
};

static void seed_seq_1234(uint64_t out[4]) {
    const uint32_t INIT_A = 0x43b0d7e5u, MULT_A = 0x931e8875u;
    const uint32_t INIT_B = 0x8b51f9ddu, MULT_B = 0x58f38dedu;
    const uint32_t MIX_L  = 0xca01f9ddu, MIX_R  = 0x4973f715u;
    uint32_t pool[4] = {0, 0, 0, 0};
    uint32_t hc = INIT_A;
    auto hashmix = [&](uint32_t v) -> uint32_t {
        v ^= hc; hc *= MULT_A; v *= hc; v ^= v >> 16; return v;
    };
    auto mix = [](uint32_t x, uint32_t y, uint32_t ml, uint32_t mr) -> uint32_t {
        uint32_t r = x * ml - y * mr; r ^= r >> 16; return r;
    };
    for (int i = 0; i < 4; i++) pool[i] = hashmix(i < 1 ? 1234u : 0u);
    for (int s = 0; s < 4; s++)
        for (int d = 0; d < 4; d++)
            if (s != d) pool[d] = mix(pool[d], hashmix(pool[s]), MIX_L, MIX_R);
    uint32_t hb = INIT_B;
    uint32_t st[8];
    for (int i = 0; i < 8; i++) {
        uint32_t dv = pool[i & 3];
        dv ^= hb; hb *= MULT_B; dv *= hb; dv ^= dv >> 16;
        st[i] = dv;
    }
    for (int i = 0; i < 4; i++)
        out[i] = (uint64_t)st[2 * i] | ((uint64_t)st[2 * i + 1] << 32);
}

static Pcg64 make_rng() {
    uint64_t w[4]; seed_seq_1234(w);
    u128_t seed128 = ((u128_t)w[0] << 64) | (u128_t)w[1];
    u128_t inc128  = ((u128_t)w[2] << 64) | (u128_t)w[3];
    Pcg64 r; r.has32 = false; r.buf32 = 0;
    r.inc = (inc128 << 1) | (u128_t)1;
    r.state = 0;
    r.step();
    r.state += seed128;
    r.step();
    return r;
}

static void choice2of4(Pcg64& r, int& c, int& t) {
    const uint64_t EMPTY = ~0ull;
    uint64_t hs[4] = {EMPTY, EMPTY, EMPTY, EMPTY};
    int64_t idx[2];
    int ls = 0;
    for (int j = 2; j <= 3; j++) {
        uint64_t val = r.bounded((uint64_t)j);
        uint64_t loc = val & 3ull;
        while (hs[loc] != EMPTY && hs[loc] != val) loc = (loc + 1) & 3ull;
        if (hs[loc] == EMPTY) { hs[loc] = val; idx[ls] = (int64_t)val; }
        else {
            loc = (uint64_t)j & 3ull;
            while (hs[loc] != EMPTY) loc = (loc + 1) & 3ull;
            hs[loc] = (uint64_t)j; idx[ls] = j;
        }
        ls++;
    }
    uint64_t jj = r.bounded(1);
    int64_t tmp = idx[1]; idx[1] = idx[jj]; idx[jj] = tmp;
    c = (int)idx[0]; t = (int)idx[1];
}

static PlanArg build_plan() {
    Pcg64 r = make_rng();
    PlanArg plan; plan.n = 0;
    for (int l = 0; l < 2; l++) {
        int i = 0;
        while (i < 4) {
            double u = r.rnd();
            if (u > 0.3) {
                int g = (int)r.bounded(2);
                int w = (int)r.bounded(3);
                if (plan.n < 24) plan.ops[plan.n] = make_int4(0, g, w, l * 4 + i);
                plan.n++;
                i++;
            } else {
                int c, t; choice2of4(r, c, t);
                if (plan.n < 24) plan.ops[plan.n] = make_int4(1, c, t, 0);
                plan.n++;
            }
        }
    }
    if (plan.n > 24) plan.n = 24;
    return plan;
}

} // namespace nprng

// ---------------------------------------------------------------------------
// Ground truth: run the reference's _make_plan with the real numpy.
// ---------------------------------------------------------------------------
static bool try_interp(const char* interp, const char* spath, PlanArg& plan) {
    char cmd[1200];
    snprintf(cmd, sizeof(cmd), "'%s' '%s' 2>/dev/null", interp, spath);
    FILE* p = popen(cmd, "r");
    if (!p) return false;
    PlanArg tmp;
    long magic = 0;
    int n = -1;
    bool ok = (fscanf(p, "%ld", &magic) == 1) && magic == 987654321L;
    ok = ok && (fscanf(p, "%d", &n) == 1) && n >= 8 && n <= 24;
    if (ok) {
        tmp.n = n;
        for (int i = 0; i < n && ok; i++) {
            int a, b, c, d;
            ok = (fscanf(p, "%d %d %d %d", &a, &b, &c, &d) == 4);
            if (ok) tmp.ops[i] = make_int4(a, b, c, d);
        }
    }
    pclose(p);
    if (!ok) return false;
    int nrot = 0; bool valid = true;
    for (int i = 0; i < n; i++) {
        int4 o = tmp.ops[i];
        if (o.x == 0) {
            valid = valid && (o.y >= 0 && o.y <= 2) && (o.z >= 0 && o.z <= 3)
                          && (o.w == nrot);
            nrot++;
        } else if (o.x == 1) {
            valid = valid && (o.y >= 0 && o.y <= 3) && (o.z >= 0 && o.z <= 3)
                          && (o.y != o.z);
        } else valid = false;
    }
    valid = valid && (nrot == 8);
    if (valid) { plan = tmp; return true; }
    return false;
}

static bool plan_from_python(PlanArg& plan) {
    const char* tmpdir = getenv("TMPDIR");
    if (!tmpdir || !*tmpdir) tmpdir = "/tmp";
    char spath[512];
    snprintf(spath, sizeof(spath), "%s/qonv_plan_v5_67499706024572.py", tmpdir);
    FILE* f = fopen(spath, "w");
    if (!f) return false;
    fputs(
"import numpy as np\n"
"rng = np.random.default_rng(1234)\n"
"ops = []\n"
"for l in range(2):\n"
"    i = 0\n"
"    while i < 4:\n"
"        if rng.random() > 0.3:\n"
"            g = ('RX', 'RY', 'RZ')[int(rng.integers(3))]\n"
"            w = int(rng.integers(4))\n"
"            ops.append((0, {'RX': 0, 'RY': 1, 'RZ': 2}[g], w, l * 4 + i))\n"
"            i += 1\n"
"        else:\n"
"            c, t = rng.choice(4, size=2, replace=False)\n"
"            ops.append((1, int(c), int(t), 0))\n"
"print(987654321)\n"
"print(len(ops))\n"
"for o in ops:\n"
"    print(o[0], o[1], o[2], o[3])\n", f);
    fclose(f);

    char exe[600]; exe[0] = 0;
    ssize_t en = readlink("/proc/self/exe", exe, sizeof(exe) - 1);
    if (en > 0) exe[en] = 0; else exe[0] = 0;

    if (exe[0] && try_interp(exe, spath, plan)) return true;
    if (try_interp("python3", spath, plan)) return true;
    if (try_interp("python", spath, plan)) return true;
    if (try_interp("/usr/bin/python3", spath, plan)) return true;
    return false;
}

// ---------------------------------------------------------------------------
// Kernel 1: build G[set][81]. 2 blocks x 64 threads. (validated round 4)
// ---------------------------------------------------------------------------
__global__ void build_G_kernel(const float* __restrict__ w1,
                               const float* __restrict__ w2, PlanArg plan) {
    const int set = blockIdx.x;
    const float* W = (set == 0) ? w1 : w2;
    const int lane = threadIdx.x;

    __shared__ float2 Amp[16][16];              // [column][row]
    __shared__ float Rs[256];

    if (lane < 16) {
        for (int r = 0; r < 16; r++)
            Amp[lane][r] = make_float2(r == lane ? 1.f : 0.f, 0.f);
        for (int o = 0; o < plan.n; o++) {
            int4 op = plan.ops[o];
            if (op.x == 0) {                    // rotation on wire op.z
                float th = W[op.w];
                float s, c; __sincosf(0.5f * th, &s, &c);
                int bit = 8 >> op.z;            // wire0 = bit3
                for (int p = 0; p < 16; p++) {
                    if (p & bit) continue;
                    float2 a0 = Amp[lane][p], a1 = Amp[lane][p | bit];
                    float2 n0, n1;
                    if (op.y == 0) {            // RX
                        n0 = make_float2(c * a0.x + s * a1.y, c * a0.y - s * a1.x);
                        n1 = make_float2(s * a0.y + c * a1.x, -s * a0.x + c * a1.y);
                    } else if (op.y == 1) {     // RY
                        n0 = make_float2(c * a0.x - s * a1.x, c * a0.y - s * a1.y);
                        n1 = make_float2(s * a0.x + c * a1.x, s * a0.y + c * a1.y);
                    } else {                    // RZ
                        n0 = make_float2(c * a0.x + s * a0.y, c * a0.y - s * a0.x);
                        n1 = make_float2(c * a1.x - s * a1.y, c * a1.y + s * a1.x);
                    }
                    Amp[lane][p] = n0; Amp[lane][p | bit] = n1;
                }
            } else {                            // CNOT ctrl=op.y tgt=op.z
                int cb = 8 >> op.y, tb = 8 >> op.z;
                for (int p = 0; p < 16; p++) {
                    if ((p & cb) && !(p & tb)) {
                        float2 t = Amp[lane][p];
                        Amp[lane][p] = Amp[lane][p | tb];
                        Amp[lane][p | tb] = t;
                    }
                }
            }
        }
    }
    __syncthreads();

    for (int e = lane; e < 256; e += 64) {
        int p = e >> 4, q = e & 15;
        float acc = 0.f;
        #pragma unroll
        for (int r = 0; r < 16; r++) {
            float zr = (r & 8) ? -1.f : 1.f;
            float2 up = Amp[p][r], uq = Amp[q][r];
            acc += zr * (up.x * uq.x + up.y * uq.y);
        }
        Rs[e] = acc;
    }
    __syncthreads();

    for (int e = lane; e < 81; e += 64) {
        int dig[4];
        dig[3] = e % 3; dig[2] = (e / 3) % 3; dig[1] = (e / 9) % 3; dig[0] = e / 27;
        int mask = 0;
        #pragma unroll
        for (int t = 0; t < 4; t++) if (dig[t] == 2) mask |= (8 >> t);
        float acc = 0.f;
        for (int p = 0; p < 16; p++) {
            float sgn = 1.f;
            #pragma unroll
            for (int t = 0; t < 4; t++)
                if (dig[t] == 1 && (p & (8 >> t))) sgn = -sgn;
            acc += sgn * Rs[p * 16 + (p ^ mask)];
        }
        g_G[set][e] = acc * 0.0625f;
    }
}

// ---------------------------------------------------------------------------
// Kernel 2: main, v5. One thread per 4 consecutive l-outputs (float4 store).
// 1,048,576 threads. Active threads load 4 rows x 16 floats (8 float4 loads);
// even/odd elements of each row feed the 4 outputs' y-values.
// ---------------------------------------------------------------------------
__global__ void __launch_bounds__(256)
qonv_g4_kernel(const float* __restrict__ x, float4* __restrict__ out,
               float diag) {
    const unsigned idx = blockIdx.x * 256u + threadIdx.x;
    const int c2 = (int)((idx >> 13) & 31u);    // uniform per block

    __shared__ float Gs[81];
    if (threadIdx.x < 81) Gs[threadIdx.x] = g_G[c2 >= 16 ? 1 : 0][threadIdx.x];
    __syncthreads();

    const int g = (int)(idx & 7u);              // l-group: l = 4g..4g+3
    const int k = (int)((idx >> 3) & 31u);
    const int j = (int)((idx >> 8) & 31u);
    const int b = (int)(idx >> 18);

    float4 res = make_float4(0.f, 0.f, 0.f, 0.f);
    if ((j < 16) & (k < 16) & (g < 4)) {
        const int c = c2 & 15;
        const float* xb = x + (size_t)(b * 16 + c) * 262144   // 64^3
                            + (size_t)(2 * j) * 4096          // J*64*64
                            + (size_t)(2 * k) * 64 + 8 * g;   // K*64 + L-base
        // rows: r00=(J,K), r01=(J,K+1), r10=(J+1,K), r11=(J+1,K+1)
        union { float4 v[2]; float f[8]; } r00, r01, r10, r11;
        r00.v[0] = *(const float4*)(xb);
        r00.v[1] = *(const float4*)(xb + 4);
        r01.v[0] = *(const float4*)(xb + 64);
        r01.v[1] = *(const float4*)(xb + 68);
        r10.v[0] = *(const float4*)(xb + 4096);
        r10.v[1] = *(const float4*)(xb + 4100);
        r11.v[0] = *(const float4*)(xb + 4160);
        r11.v[1] = *(const float4*)(xb + 4164);

        float o4[4];
        #pragma unroll
        for (int i = 0; i < 4; i++) {
            const int e = 2 * i, od = 2 * i + 1;
            float y0, y1, y2, y3;
            if (c2 < 16) {   // circuit 1: (0,0,0),(1,1,0),(0,1,1),(1,0,1)
                y0 = r00.f[e];  y1 = r11.f[e];  y2 = r01.f[od]; y3 = r10.f[od];
            } else {         // circuit 2: (1,1,1),(0,0,1),(1,0,0),(0,1,0)
                y0 = r11.f[od]; y1 = r00.f[od]; y2 = r10.f[e];  y3 = r01.f[e];
            }
            float C0, S0, C1, S1, C2, S2, C3, S3;
            {
                float a0 = 0.5f * fminf(1.f, y0);   // revolutions
                float a1 = 0.5f * fminf(1.f, y1);
                float a2 = 0.5f * fminf(1.f, y2);
                float a3 = 0.5f * fminf(1.f, y3);
                C0 = __builtin_amdgcn_cosf(a0); S0 = __builtin_amdgcn_sinf(a0);
                C1 = __builtin_amdgcn_cosf(a1); S1 = __builtin_amdgcn_sinf(a1);
                C2 = __builtin_amdgcn_cosf(a2); S2 = __builtin_amdgcn_sinf(a2);
                C3 = __builtin_amdgcn_cosf(a3); S3 = __builtin_amdgcn_sinf(a3);
            }
            float A[27];
            #pragma unroll
            for (int q = 0; q < 27; q++)
                A[q] = fmaf(S3, Gs[3 * q + 2], fmaf(C3, Gs[3 * q + 1], Gs[3 * q]));
            float B[9];
            #pragma unroll
            for (int q = 0; q < 9; q++)
                B[q] = fmaf(S2, A[3 * q + 2], fmaf(C2, A[3 * q + 1], A[3 * q]));
            float D[3];
            #pragma unroll
            for (int q = 0; q < 3; q++)
                D[q] = fmaf(S1, B[3 * q + 2], fmaf(C1, B[3 * q + 1], B[3 * q]));
            o4[i] = fmaf(S0, D[2], fmaf(C0, D[1], D[0]));
        }
        res = make_float4(o4[0], o4[1], o4[2], o4[3]);
    }
    if (idx == 0) res.x += diag;   // diagnostic sentinel (0 normally)
    out[idx] = res;
}

// ---------------------------------------------------------------------------
extern "C" void kernel_launch(void* const* d_in, const int* in_sizes, int n_in,
                              void* d_out, int out_size, void* d_ws, size_t ws_size,
                              hipStream_t stream) {
    (void)in_sizes; (void)n_in; (void)out_size; (void)d_ws; (void)ws_size;
    const float* x  = (const float*)d_in[0];
    const float* w1 = (const float*)d_in[1];
    const float* w2 = (const float*)d_in[2];
    float4* out = (float4*)d_out;

    // Plan is a pure function of SEED=1234; computed once on the first
    // (pre-capture) call and cached -> identical GPU work every call.
    static PlanArg g_plan;
    static float g_diag = 0.f;
    static bool g_ready = false;
    if (!g_ready) {
        if (!plan_from_python(g_plan)) {
            g_plan = nprng::build_plan();
            g_diag = 1000.f;   // signal: python ground-truth path unavailable
        }
        g_ready = true;
    }

    build_G_kernel<<<dim3(2), dim3(64), 0, stream>>>(w1, w2, g_plan);

    const unsigned nthreads = 1048576u;  // 4,194,304 outputs / 4
    qonv_g4_kernel<<<dim3(nthreads / 256u), dim3(256), 0, stream>>>(
        x, out, g_diag);
}